// Round 20
// baseline (196.141 us; speedup 1.0000x reference)
//
#include <hip/hip_runtime.h>

#define N 343        // 7*7*7 tokens per window
#define NP 352       // padded to 11 tiles of 32
#define DIM 128
#define HEADS 4
#define DH 32

typedef float  f32x16 __attribute__((ext_vector_type(16)));
typedef float  float4v __attribute__((ext_vector_type(4)));
typedef short  short8 __attribute__((ext_vector_type(8)));
typedef unsigned uint4v __attribute__((ext_vector_type(4)));
typedef unsigned uint2v __attribute__((ext_vector_type(2)));

#define MFMA __builtin_amdgcn_mfma_f32_32x32x16_bf16

// ---- gfx950 packed bf16 convert (RNE) and cross-half swap -----------------
static __device__ __forceinline__ unsigned cvtpk_bf16(float lo, float hi) {
  unsigned r;
  asm("v_cvt_pk_bf16_f32 %0, %1, %2" : "=v"(r) : "v"(lo), "v"(hi));
  return r;
}
static __device__ __forceinline__ void swap32(unsigned &a, unsigned &b) {
  asm("v_permlane32_swap_b32 %0, %1" : "+v"(a), "+v"(b));
}
// native base-2 exponential (v_exp_f32 IS exp2 on CDNA)
static __device__ __forceinline__ float exp2v(float x) {
  float r;
  asm("v_exp_f32 %0, %1" : "=v"(r) : "v"(x));
  return r;
}
// 3-input max, single VOP3 instruction
static __device__ __forceinline__ float max3v(float a, float b, float c) {
  float r;
  asm("v_max3_f32 %0, %1, %2, %3" : "=v"(r) : "v"(a), "v"(b), "v"(c));
  return r;
}
static __device__ __forceinline__ unsigned short bf16u(float a) {
  unsigned u = __builtin_bit_cast(unsigned, a);
  unsigned r = u + 0x7fffu + ((u >> 16) & 1u);
  return (unsigned short)(r >> 16);
}

// ---------------------------------------------------------------------------
// Kernel 1: bias gather pre-permuted into the 32x32 MFMA C-fragment order.
// ---------------------------------------------------------------------------
__global__ __launch_bounds__(256) void bias_kernel(
    const float* __restrict__ table, const int* __restrict__ rel,
    float* __restrict__ prep) {
  int row = blockIdx.x * 256 + threadIdx.x;
  if (row >= HEADS * 11 * 2 * NP) return;
  int i = row % NP;
  int t = row / NP;
  int half = t & 1;
  int tj = t >> 1;
  int jt = tj % 11;
  int h = tj / 11;
  float* dst = prep + (size_t)row * 16;
#pragma unroll
  for (int r = 0; r < 16; ++r) {
    int j = jt * 32 + (r & 3) + ((r >> 2) << 3) + (half << 2);
    float v;
    if (j >= N) v = -1.44e30f;
    else if (i >= N) v = 0.f;
    else v = table[rel[i * N + j] * HEADS + h] * 1.4426950408889634f;
    dst[r] = v;
  }
}

// ---------------------------------------------------------------------------
// Phase-2 flash loop, one 32-row M-tile, Q in registers. Max-tracked online
// softmax (no-max failed twice — permanent). v_max3 tree (8 ops, depth 3).
// NEW: cross-half l-reduce deferred to epilogue (rescale factor f is
// wave-uniform, sum associative) — removes 1 shfl/jt from the serial chain.
// Kb: [352][40] col-swizzled by (row&24). Vt: [32][360] token-swizzled
// (d&24). Bank conflicts NOT on the critical path (measured R11 vs R14).
// ---------------------------------------------------------------------------
static __device__ __forceinline__ void attend(
    int i0, uint4v qAu, uint4v qBu,
    const unsigned short* __restrict__ Kb, const unsigned short* __restrict__ Vt,
    const float* __restrict__ bp, float* __restrict__ outw,
    int l31, int half, int swz) {
  short8 q0 = __builtin_bit_cast(short8, qAu);
  short8 q1 = __builtin_bit_cast(short8, qBu);
  const float* bpi = bp + (size_t)(i0 + l31) * 16;

  f32x16 O;
#pragma unroll
  for (int r = 0; r < 16; ++r) O[r] = 0.f;
  float m_run = -3.0e38f, l_run = 0.f;

  f32x16 Tn = *(const f32x16*)(bpi);      // prefetch bias tile 0
  for (int jt = 0; jt < 11; ++jt) {
    f32x16 T = Tn;                        // bias IS the MFMA C-input
    if (jt < 10) Tn = *(const f32x16*)(bpi + (size_t)(jt + 1) * 11264);

    const int krow = (jt * 32 + l31) * 40;
    short8 ka0 = *(const short8*)&Kb[krow + ((half * 8) ^ swz)];
    short8 ka1 = *(const short8*)&Kb[krow + ((half * 8 + 16) ^ swz)];
    T = MFMA(ka0, q0, T, 0, 0, 0);
    T = MFMA(ka1, q1, T, 0, 0, 0);

    // row max via v_max3 tree: 5 + 2 + 1 = 8 ops, depth 3
    float g0 = max3v(T[0],  T[1],  T[2]);
    float g1 = max3v(T[3],  T[4],  T[5]);
    float g2 = max3v(T[6],  T[7],  T[8]);
    float g3 = max3v(T[9],  T[10], T[11]);
    float g4 = max3v(T[12], T[13], T[14]);
    float h0 = max3v(g0, g1, g2);
    float h1 = max3v(g3, g4, T[15]);
    float pm = fmaxf(h0, h1);
    pm = fmaxf(pm, __shfl_xor(pm, 32, 64));

    if (__any(pm > m_run + 11.5f)) {      // deferred-max rescale (rare)
      float nm = fmaxf(m_run, pm);
      float f = exp2v(m_run - nm);        // wave-uniform
      l_run *= f;
      m_run = nm;
#pragma unroll
      for (int r = 0; r < 16; ++r) {
        int iD = (r & 3) + ((r >> 2) << 3) + (half << 2);
        O[r] *= __shfl(f, iD, 64);
      }
    }

    float p[16];
#pragma unroll
    for (int r = 0; r < 16; ++r) p[r] = exp2v(T[r] - m_run);
    float s0 = (p[0] + p[1]) + (p[2] + p[3]);
    float s1 = (p[4] + p[5]) + (p[6] + p[7]);
    float s2 = (p[8] + p[9]) + (p[10] + p[11]);
    float s3 = (p[12] + p[13]) + (p[14] + p[15]);
    l_run += (s0 + s1) + (s2 + s3);       // per-half partial; reduced at end

    unsigned k0 = cvtpk_bf16(p[0], p[1]),   k1 = cvtpk_bf16(p[2], p[3]);
    unsigned k2 = cvtpk_bf16(p[4], p[5]),   k3 = cvtpk_bf16(p[6], p[7]);
    unsigned k4 = cvtpk_bf16(p[8], p[9]),   k5 = cvtpk_bf16(p[10], p[11]);
    unsigned k6 = cvtpk_bf16(p[12], p[13]), k7 = cvtpk_bf16(p[14], p[15]);
    swap32(k0, k2); swap32(k1, k3); swap32(k4, k6); swap32(k5, k7);
    uint4v u1 = {k0, k1, k2, k3};
    uint4v u2 = {k4, k5, k6, k7};
    short8 pa1 = __builtin_bit_cast(short8, u1);
    short8 pa2 = __builtin_bit_cast(short8, u2);

    const int vrow = l31 * 360 + jt * 32;
    short8 vb1 = *(const short8*)&Vt[vrow + ((half * 8) ^ swz)];
    short8 vb2 = *(const short8*)&Vt[vrow + ((half * 8 + 16) ^ swz)];
    O = MFMA(pa1, vb1, O, 0, 0, 0);
    O = MFMA(pa2, vb2, O, 0, 0, 0);
  }

  l_run += __shfl_xor(l_run, 32, 64);     // single deferred cross-half reduce
  float inv = 1.0f / l_run;
#pragma unroll
  for (int r = 0; r < 16; ++r) {
    int iD = (r & 3) + ((r >> 2) << 3) + (half << 2);
    float invr = __shfl(inv, iD, 64);
    int i = i0 + iD;
    if (i < N) outw[(size_t)i * DIM + l31] = O[r] * invr;
  }
}

// ---------------------------------------------------------------------------
// Kernel 2: fused QKV projection + attention. NEW vs R19: 384 threads =
// 6 waves, TWO M-tiles per wave -> per-block LDS 59.9KB x2 = 119.8 <= 160KB
// and ~150 regs/wave <= 170 -> TWO blocks resident per CU (12 waves total,
// same as before, but two independent barrier domains: block A's phase-2
// VALU overlaps block B's phase-1 MFMA/mem; inter-block boundaries overlap).
// W fragments shared across a wave's 2 tiles -> phase-1 ds_reads halve.
// W resident in Wf[96][136] (68 dw == 4 mod 32, conflict-free); X dbuf,
// one barrier per kc; T14 load-issue placement.
// ---------------------------------------------------------------------------
__global__ __launch_bounds__(384, 3) void attn_kernel(
    const float* __restrict__ x, const float* __restrict__ wqkv,
    const float* __restrict__ prep, float* __restrict__ out) {
  const int b = blockIdx.x;
  const int sw = (b & 7) * ((int)gridDim.x >> 3) + (b >> 3);  // XCD swizzle
  const int h = sw & 3;
  const int w = sw >> 2;
  const int tid = threadIdx.x;
  const int lane = tid & 63;
  const int wv = tid >> 6;        // 0..5
  const int l31 = lane & 31;
  const int half = lane >> 5;

  __shared__ __align__(16) unsigned short lds[29952];   // 59904 B
  unsigned short* Xb0 = lds;            // [352][24]  (phase 1, buf 0)
  unsigned short* Xb1 = lds + 8448;     // [352][24]  (phase 1, buf 1)
  unsigned short* Wf  = lds + 16896;    // [96][136]  (phase 1, resident W)
  unsigned short* Kb = lds;             // [352][40]  (phase 2, aliased)
  unsigned short* Vt = lds + 14080;     // [32][360]

  const float* xw = x + (size_t)w * (N * DIM);
  const int xsw = ((l31 >> 3) & 1) << 3;   // 1-bit swizzle for X frag reads
  const int mt0 = wv;
  const bool two = (wv < 5);
  const int mt1 = two ? wv + 6 : 5;     // clamped; guarded by `two`

  // ---- staging geometry: 1408 quad-jobs over 384 threads = jobs A..D ----
  const int xrowA = tid >> 2,          xgA = (tid & 3) << 2;
  const int xrowB = (tid + 384) >> 2,  xgB = ((tid + 384) & 3) << 2;
  const int xrowC = (tid + 768) >> 2,  xgC = ((tid + 768) & 3) << 2;
  const int xrowD = (tid + 1152) >> 2, xgD = ((tid + 1152) & 3) << 2;
  const bool hasD = (tid < 256);
  const int xgsA = xgA ^ (((xrowA >> 3) & 1) << 3);
  const int xgsB = xgB ^ (((xrowB >> 3) & 1) << 3);
  const int xgsC = xgC ^ (((xrowC >> 3) & 1) << 3);
  const int xgsD = xgD ^ (((xrowD >> 3) & 1) << 3);

  float4v xrA = {0.f, 0.f, 0.f, 0.f}, xrB = {0.f, 0.f, 0.f, 0.f};
  float4v xrC = {0.f, 0.f, 0.f, 0.f}, xrD = {0.f, 0.f, 0.f, 0.f};

#define LOAD_STAGE(kc_)                                                     \
  {                                                                         \
    xrA = *(const float4v*)(xw + xrowA * DIM + (kc_) * 16 + xgA);           \
    xrB = *(const float4v*)(xw + xrowB * DIM + (kc_) * 16 + xgB);           \
    xrC = *(const float4v*)(xw + xrowC * DIM + (kc_) * 16 + xgC);           \
    xrD[0] = 0.f; xrD[1] = 0.f; xrD[2] = 0.f; xrD[3] = 0.f;                 \
    if (hasD && xrowD < N)                                                  \
      xrD = *(const float4v*)(xw + xrowD * DIM + (kc_) * 16 + xgD);         \
  }

#define WRITE_STAGE(XB_)                                                    \
  {                                                                         \
    uint2v v0 = {cvtpk_bf16(xrA[0], xrA[1]), cvtpk_bf16(xrA[2], xrA[3])};   \
    uint2v v1 = {cvtpk_bf16(xrB[0], xrB[1]), cvtpk_bf16(xrB[2], xrB[3])};   \
    uint2v v2 = {cvtpk_bf16(xrC[0], xrC[1]), cvtpk_bf16(xrC[2], xrC[3])};   \
    *(uint2v*)&(XB_)[xrowA * 24 + xgsA] = v0;                               \
    *(uint2v*)&(XB_)[xrowB * 24 + xgsB] = v1;                               \
    *(uint2v*)&(XB_)[xrowC * 24 + xgsC] = v2;                               \
    if (hasD) {                                                             \
      uint2v v3 = {cvtpk_bf16(xrD[0], xrD[1]), cvtpk_bf16(xrD[2], xrD[3])}; \
      *(uint2v*)&(XB_)[xrowD * 24 + xgsD] = v3;                             \
    }                                                                       \
  }

  f32x16 aQ0, aK0, aV0, aQ1, aK1, aV1;
#pragma unroll
  for (int r = 0; r < 16; ++r) {
    aQ0[r] = 0.f; aK0[r] = 0.f; aV0[r] = 0.f;
    aQ1[r] = 0.f; aK1[r] = 0.f; aV1[r] = 0.f;
  }

  // ---------------- Phase 1 prologue: X chunk 0 + resident W ----------------
  LOAD_STAGE(0);
  // one-time W stage: 3072 jobs (c 0..95, k-groups of 4), 8 per thread
#pragma unroll
  for (int p = 0; p < 8; ++p) {
    int idx = tid + p * 384;
    int c = idx % 96, kg = (idx / 96) << 2;
    int col = ((c >> 5) << 7) + h * DH + (c & 31);
    const float* wp = wqkv + (size_t)kg * 384 + col;
#pragma unroll
    for (int u = 0; u < 4; ++u)
      Wf[c * 136 + kg + u] = bf16u(wp[(size_t)u * 384]);
  }

  // ---------------- Phase 1 main: one barrier per kc ----------------
  for (int kc = 0; kc < 8; ++kc) {
    unsigned short* cur = (kc & 1) ? Xb1 : Xb0;
    WRITE_STAGE(cur);                 // regs from LOAD of last iter
    if (kc < 7) LOAD_STAGE(kc + 1);   // issue next chunk's loads NOW
    __syncthreads();                  // cur visible; (kc-2) reads retired

    const int fo = (half * 8) ^ xsw;
    const int wfo = kc * 16 + half * 8;
    short8 xh0 = *(const short8*)&cur[(mt0 * 32 + l31) * 24 + fo];
    short8 xh1 = xh0;
    if (two) xh1 = *(const short8*)&cur[(mt1 * 32 + l31) * 24 + fo];
    {  // Q: TRANSPOSED -> A = Wq, B = X (W frag shared by both tiles)
      short8 wh8 = *(const short8*)&Wf[l31 * 136 + wfo];
      aQ0 = MFMA(wh8, xh0, aQ0, 0, 0, 0);
      if (two) aQ1 = MFMA(wh8, xh1, aQ1, 0, 0, 0);
    }
    {  // K: A = X, B = Wk
      short8 wh8 = *(const short8*)&Wf[(32 + l31) * 136 + wfo];
      aK0 = MFMA(xh0, wh8, aK0, 0, 0, 0);
      if (two) aK1 = MFMA(xh1, wh8, aK1, 0, 0, 0);
    }
    {  // V: A = X, B = Wv
      short8 wh8 = *(const short8*)&Wf[(64 + l31) * 136 + wfo];
      aV0 = MFMA(xh0, wh8, aV0, 0, 0, 0);
      if (two) aV1 = MFMA(xh1, wh8, aV1, 0, 0, 0);
    }
  }

  __syncthreads();  // all X/W reads done; safe to overwrite with K/V

  // ---- Q^T acc -> phase-2 B-fragment, fully in registers ----
  const float QS = 0.17677669529663687f * 1.4426950408889634f;  // /sqrt(32)*log2e
  uint4v qA0 = {0, 0, 0, 0}, qB0 = {0, 0, 0, 0};
  uint4v qA1 = {0, 0, 0, 0}, qB1 = {0, 0, 0, 0};
  const int swz = ((l31 >> 3) & 3) << 3;
  {
    unsigned g0 = cvtpk_bf16(aQ0[0] * QS, aQ0[1] * QS);
    unsigned g1 = cvtpk_bf16(aQ0[2] * QS, aQ0[3] * QS);
    unsigned g2 = cvtpk_bf16(aQ0[4] * QS, aQ0[5] * QS);
    unsigned g3 = cvtpk_bf16(aQ0[6] * QS, aQ0[7] * QS);
    unsigned g4 = cvtpk_bf16(aQ0[8] * QS, aQ0[9] * QS);
    unsigned g5 = cvtpk_bf16(aQ0[10] * QS, aQ0[11] * QS);
    unsigned g6 = cvtpk_bf16(aQ0[12] * QS, aQ0[13] * QS);
    unsigned g7 = cvtpk_bf16(aQ0[14] * QS, aQ0[15] * QS);
    swap32(g0, g2); swap32(g1, g3); swap32(g4, g6); swap32(g5, g7);
    qA0[0] = g0; qA0[1] = g1; qA0[2] = g2; qA0[3] = g3;
    qB0[0] = g4; qB0[1] = g5; qB0[2] = g6; qB0[3] = g7;
  }
  if (two) {
    unsigned g0 = cvtpk_bf16(aQ1[0] * QS, aQ1[1] * QS);
    unsigned g1 = cvtpk_bf16(aQ1[2] * QS, aQ1[3] * QS);
    unsigned g2 = cvtpk_bf16(aQ1[4] * QS, aQ1[5] * QS);
    unsigned g3 = cvtpk_bf16(aQ1[6] * QS, aQ1[7] * QS);
    unsigned g4 = cvtpk_bf16(aQ1[8] * QS, aQ1[9] * QS);
    unsigned g5 = cvtpk_bf16(aQ1[10] * QS, aQ1[11] * QS);
    unsigned g6 = cvtpk_bf16(aQ1[12] * QS, aQ1[13] * QS);
    unsigned g7 = cvtpk_bf16(aQ1[14] * QS, aQ1[15] * QS);
    swap32(g0, g2); swap32(g1, g3); swap32(g4, g6); swap32(g5, g7);
    qA1[0] = g0; qA1[1] = g1; qA1[2] = g2; qA1[3] = g3;
    qB1[0] = g4; qB1[1] = g5; qB1[2] = g6; qB1[3] = g7;
  }

  // ---- K -> LDS (2-bit XOR col swizzle), V -> LDS transposed ----
#pragma unroll
  for (int r = 0; r < 16; ++r) {
    int iD = (r & 3) + ((r >> 2) << 3) + (half << 2);
    int cs = l31 ^ ((r >> 2) << 3);
    Kb[(mt0 * 32 + iD) * 40 + cs] = bf16u(aK0[r]);
    if (two) Kb[(mt1 * 32 + iD) * 40 + cs] = bf16u(aK1[r]);
  }
#pragma unroll
  for (int r = 0; r < 16; r += 2) {
    int j0 = (r & 3) + ((r >> 2) << 3) + (half << 2);
    *(unsigned*)&Vt[l31 * 360 + mt0 * 32 + (j0 ^ swz)] =
        cvtpk_bf16(aV0[r], aV0[r + 1]);
    if (two)
      *(unsigned*)&Vt[l31 * 360 + mt1 * 32 + (j0 ^ swz)] =
          cvtpk_bf16(aV1[r], aV1[r + 1]);
  }
  __syncthreads();

  // ---------------- Phase 2: attention (2 tiles sequentially) ----------------
  const float* bp = prep + ((size_t)(h * 22 + half) * NP) * 16;
  float* outw = out + (size_t)w * N * DIM + h * DH;
  attend(mt0 * 32, qA0, qB0, Kb, Vt, bp, outw, l31, half, swz);
  if (two) attend(mt1 * 32, qA1, qB1, Kb, Vt, bp, outw, l31, half, swz);
}

// ---------------------------------------------------------------------------
// Kernel 3: out-projection, in-place on d_out. Pure bf16 GEMM (O and W2
// single bf16). One block per window, 768 threads, M-tile per wave.
// ---------------------------------------------------------------------------
__global__ __launch_bounds__(768, 3) void proj_kernel(
    const float* __restrict__ wout, float* __restrict__ out) {
  const int w = blockIdx.x;
  const int tid = threadIdx.x;
  const int lane = tid & 63, wv = tid >> 6, l31 = lane & 31, half = lane >> 5;
  __shared__ __align__(16) unsigned short lds[19200];     // 38400 B
  unsigned short* Oh = lds;               // [352][40]
  unsigned short* W2h = lds + 14080;      // [128][40]
  float* ow = out + (size_t)w * N * DIM;
  const int swz = ((l31 >> 3) & 3) << 3;
  const bool act = (wv < 11);

  f32x16 acc[4];
#pragma unroll
  for (int s = 0; s < 4; ++s)
#pragma unroll
    for (int r = 0; r < 16; ++r) acc[s][r] = 0.f;

  for (int kc = 0; kc < 4; ++kc) {
    __syncthreads();
    // O staging: 2816 quad-groups (hi only)
#pragma unroll
    for (int p = 0; p < 4; ++p) {
      int idx = tid + p * 768;
      if (idx < 2816) {
        int row = idx >> 3, g = (idx & 7) << 2;
        float4v v = {0.f, 0.f, 0.f, 0.f};
        if (row < N) v = *(const float4v*)(ow + row * DIM + kc * 32 + g);
        unsigned h0 = cvtpk_bf16(v[0], v[1]);
        unsigned h1 = cvtpk_bf16(v[2], v[3]);
        uint2v hv = {h0, h1};
        int gs = g ^ (((row >> 3) & 3) << 3);
        *(uint2v*)&Oh[row * 40 + gs] = hv;
      }
    }
    // W2 staging: 1024 quad-jobs (hi only)
#pragma unroll
    for (int p = 0; p < 2; ++p) {
      int idx = tid + p * 768;
      if (idx < 1024) {
        int k = idx >> 5, n4 = (idx & 31) << 2;
        float4v v = *(const float4v*)(wout + (size_t)(kc * 32 + k) * DIM + n4);
#pragma unroll
        for (int u = 0; u < 4; ++u) {
          int n = n4 + u;
          int ks = k ^ (((n >> 3) & 3) << 3);
          W2h[n * 40 + ks] = bf16u(v[u]);
        }
      }
    }
    __syncthreads();
    if (act) {
#pragma unroll
      for (int kk = 0; kk < 2; ++kk) {
        int ro = (kk * 16 + half * 8) ^ swz;
        int rb = (wv * 32 + l31) * 40 + ro;
        short8 ah = *(const short8*)&Oh[rb];
#pragma unroll
        for (int s = 0; s < 4; ++s) {
          short8 bh = *(const short8*)&W2h[(s * 32 + l31) * 40 + ro];
          acc[s] = MFMA(ah, bh, acc[s], 0, 0, 0);
        }
      }
    }
  }
  if (act) {
#pragma unroll
    for (int s = 0; s < 4; ++s) {
#pragma unroll
      for (int r = 0; r < 16; ++r) {
        int iD = (r & 3) + ((r >> 2) << 3) + (half << 2);
        int i = wv * 32 + iD;
        if (i < N) ow[(size_t)i * DIM + s * 32 + l31] = acc[s][r];
      }
    }
  }
}

// ---------------------------------------------------------------------------
extern "C" void kernel_launch(void* const* d_in, const int* in_sizes, int n_in,
                              void* d_out, int out_size, void* d_ws, size_t ws_size,
                              hipStream_t stream) {
  const float* x     = (const float*)d_in[0];
  const float* wqkv  = (const float*)d_in[1];
  const float* wout  = (const float*)d_in[2];
  const float* table = (const float*)d_in[3];
  const int*   rel   = (const int*)d_in[4];
  float* out  = (float*)d_out;
  float* prep = (float*)d_ws;  // 4*11*2*352*16*4 B = 1.98 MB

  const int B = in_sizes[0] / (N * DIM);  // 512 windows
  const int rows = HEADS * 11 * 2 * NP;   // 30976

  bias_kernel<<<(rows + 255) / 256, 256, 0, stream>>>(table, rel, prep);
  attn_kernel<<<HEADS * B, 384, 0, stream>>>(x, wqkv, prep, out);
  proj_kernel<<<B, 768, 0, stream>>>(wout, out);
}

// Round 21
// 165.279 us; speedup vs baseline: 1.1867x; 1.1867x over previous
//
#include <hip/hip_runtime.h>

#define N 343        // 7*7*7 tokens per window
#define NP 352       // padded to 11 tiles of 32
#define DIM 128
#define HEADS 4
#define DH 32

typedef float  f32x16 __attribute__((ext_vector_type(16)));
typedef float  float4v __attribute__((ext_vector_type(4)));
typedef short  short8 __attribute__((ext_vector_type(8)));
typedef unsigned uint4v __attribute__((ext_vector_type(4)));
typedef unsigned uint2v __attribute__((ext_vector_type(2)));

#define MFMA __builtin_amdgcn_mfma_f32_32x32x16_bf16

// ---- gfx950 packed bf16 convert (RNE) and cross-half swap -----------------
static __device__ __forceinline__ unsigned cvtpk_bf16(float lo, float hi) {
  unsigned r;
  asm("v_cvt_pk_bf16_f32 %0, %1, %2" : "=v"(r) : "v"(lo), "v"(hi));
  return r;
}
static __device__ __forceinline__ void swap32(unsigned &a, unsigned &b) {
  asm("v_permlane32_swap_b32 %0, %1" : "+v"(a), "+v"(b));
}
// native base-2 exponential (v_exp_f32 IS exp2 on CDNA)
static __device__ __forceinline__ float exp2v(float x) {
  float r;
  asm("v_exp_f32 %0, %1" : "=v"(r) : "v"(x));
  return r;
}
// 3-input max, single VOP3 instruction
static __device__ __forceinline__ float max3v(float a, float b, float c) {
  float r;
  asm("v_max3_f32 %0, %1, %2, %3" : "=v"(r) : "v"(a), "v"(b), "v"(c));
  return r;
}
static __device__ __forceinline__ unsigned short bf16u(float a) {
  unsigned u = __builtin_bit_cast(unsigned, a);
  unsigned r = u + 0x7fffu + ((u >> 16) & 1u);
  return (unsigned short)(r >> 16);
}

// ---------------------------------------------------------------------------
// Kernel 1: bias gather pre-permuted into the 32x32 MFMA C-fragment order.
// ---------------------------------------------------------------------------
__global__ __launch_bounds__(256) void bias_kernel(
    const float* __restrict__ table, const int* __restrict__ rel,
    float* __restrict__ prep) {
  int row = blockIdx.x * 256 + threadIdx.x;
  if (row >= HEADS * 11 * 2 * NP) return;
  int i = row % NP;
  int t = row / NP;
  int half = t & 1;
  int tj = t >> 1;
  int jt = tj % 11;
  int h = tj / 11;
  float* dst = prep + (size_t)row * 16;
#pragma unroll
  for (int r = 0; r < 16; ++r) {
    int j = jt * 32 + (r & 3) + ((r >> 2) << 3) + (half << 2);
    float v;
    if (j >= N) v = -1.44e30f;
    else if (i >= N) v = 0.f;
    else v = table[rel[i * N + j] * HEADS + h] * 1.4426950408889634f;
    dst[r] = v;
  }
}

// ---------------------------------------------------------------------------
// Phase-2 flash loop, one 32-row M-tile, Q in registers. Max-tracked online
// softmax (no-max failed twice — permanent). v_max3 tree (8 ops, depth 3).
// Cross-half l-reduce deferred to epilogue (verified correct in R20; the
// rescale factor f is wave-uniform, sum associative) — removes 1 shfl/jt
// from the serial chain. Kb: [352][40] col-swizzled by (row&24).
// Vt: [32][360] token-swizzled (d&24). Bank conflicts NOT on the critical
// path (measured R11 vs R14: 1.45e7 vs 1.85e7 cyc, identical duration).
// ---------------------------------------------------------------------------
static __device__ __forceinline__ void attend(
    int i0, uint4v qAu, uint4v qBu,
    const unsigned short* __restrict__ Kb, const unsigned short* __restrict__ Vt,
    const float* __restrict__ bp, float* __restrict__ outw,
    int l31, int half, int swz) {
  short8 q0 = __builtin_bit_cast(short8, qAu);
  short8 q1 = __builtin_bit_cast(short8, qBu);
  const float* bpi = bp + (size_t)(i0 + l31) * 16;

  f32x16 O;
#pragma unroll
  for (int r = 0; r < 16; ++r) O[r] = 0.f;
  float m_run = -3.0e38f, l_run = 0.f;

  f32x16 Tn = *(const f32x16*)(bpi);      // prefetch bias tile 0
  for (int jt = 0; jt < 11; ++jt) {
    f32x16 T = Tn;                        // bias IS the MFMA C-input
    if (jt < 10) Tn = *(const f32x16*)(bpi + (size_t)(jt + 1) * 11264);

    const int krow = (jt * 32 + l31) * 40;
    short8 ka0 = *(const short8*)&Kb[krow + ((half * 8) ^ swz)];
    short8 ka1 = *(const short8*)&Kb[krow + ((half * 8 + 16) ^ swz)];
    T = MFMA(ka0, q0, T, 0, 0, 0);
    T = MFMA(ka1, q1, T, 0, 0, 0);

    // row max via v_max3 tree: 5 + 2 + 1 = 8 ops, depth 3
    float g0 = max3v(T[0],  T[1],  T[2]);
    float g1 = max3v(T[3],  T[4],  T[5]);
    float g2 = max3v(T[6],  T[7],  T[8]);
    float g3 = max3v(T[9],  T[10], T[11]);
    float g4 = max3v(T[12], T[13], T[14]);
    float h0 = max3v(g0, g1, g2);
    float h1 = max3v(g3, g4, T[15]);
    float pm = fmaxf(h0, h1);
    pm = fmaxf(pm, __shfl_xor(pm, 32, 64));

    if (__any(pm > m_run + 11.5f)) {      // deferred-max rescale (rare)
      float nm = fmaxf(m_run, pm);
      float f = exp2v(m_run - nm);        // wave-uniform
      l_run *= f;
      m_run = nm;
#pragma unroll
      for (int r = 0; r < 16; ++r) {
        int iD = (r & 3) + ((r >> 2) << 3) + (half << 2);
        O[r] *= __shfl(f, iD, 64);
      }
    }

    float p[16];
#pragma unroll
    for (int r = 0; r < 16; ++r) p[r] = exp2v(T[r] - m_run);
    float s0 = (p[0] + p[1]) + (p[2] + p[3]);
    float s1 = (p[4] + p[5]) + (p[6] + p[7]);
    float s2 = (p[8] + p[9]) + (p[10] + p[11]);
    float s3 = (p[12] + p[13]) + (p[14] + p[15]);
    l_run += (s0 + s1) + (s2 + s3);       // per-half partial; reduced at end

    unsigned k0 = cvtpk_bf16(p[0], p[1]),   k1 = cvtpk_bf16(p[2], p[3]);
    unsigned k2 = cvtpk_bf16(p[4], p[5]),   k3 = cvtpk_bf16(p[6], p[7]);
    unsigned k4 = cvtpk_bf16(p[8], p[9]),   k5 = cvtpk_bf16(p[10], p[11]);
    unsigned k6 = cvtpk_bf16(p[12], p[13]), k7 = cvtpk_bf16(p[14], p[15]);
    swap32(k0, k2); swap32(k1, k3); swap32(k4, k6); swap32(k5, k7);
    uint4v u1 = {k0, k1, k2, k3};
    uint4v u2 = {k4, k5, k6, k7};
    short8 pa1 = __builtin_bit_cast(short8, u1);
    short8 pa2 = __builtin_bit_cast(short8, u2);

    const int vrow = l31 * 360 + jt * 32;
    short8 vb1 = *(const short8*)&Vt[vrow + ((half * 8) ^ swz)];
    short8 vb2 = *(const short8*)&Vt[vrow + ((half * 8 + 16) ^ swz)];
    O = MFMA(pa1, vb1, O, 0, 0, 0);
    O = MFMA(pa2, vb2, O, 0, 0, 0);
  }

  l_run += __shfl_xor(l_run, 32, 64);     // single deferred cross-half reduce
  float inv = 1.0f / l_run;
#pragma unroll
  for (int r = 0; r < 16; ++r) {
    int iD = (r & 3) + ((r >> 2) << 3) + (half << 2);
    float invr = __shfl(inv, iD, 64);
    int i = i0 + iD;
    if (i < N) outw[(size_t)i * DIM + l31] = O[r] * invr;
  }
}

// ---------------------------------------------------------------------------
// Kernel 2: fused QKV projection + attention. One block per (window, head),
// 768 threads = 12 waves, one M-tile per wave (wave 11 = staging helper).
// (R20's 384-thread/2-tile variant regressed: 172 regs/wave -> 1 block/CU,
// occupancy 16.9%. This 768-thread form is the measured best structure.)
// W (head slice, 24KB bf16) staged ONCE into resident LDS Wf[96][136]
// (68 dw == 4 mod 32 -> conflict-free, no swizzle); X double-buffered ->
// one barrier per kc; T14 load-issue placement.
// ---------------------------------------------------------------------------
__global__ __launch_bounds__(768, 3) void attn_kernel(
    const float* __restrict__ x, const float* __restrict__ wqkv,
    const float* __restrict__ prep, float* __restrict__ out) {
  const int b = blockIdx.x;
  const int sw = (b & 7) * ((int)gridDim.x >> 3) + (b >> 3);  // XCD swizzle
  const int h = sw & 3;
  const int w = sw >> 2;
  const int tid = threadIdx.x;
  const int lane = tid & 63;
  const int wv = tid >> 6;        // 0..11
  const int l31 = lane & 31;
  const int half = lane >> 5;

  __shared__ __align__(16) unsigned short lds[29952];   // 59904 B
  unsigned short* Xb0 = lds;            // [352][24]  (phase 1, buf 0)
  unsigned short* Xb1 = lds + 8448;     // [352][24]  (phase 1, buf 1)
  unsigned short* Wf  = lds + 16896;    // [96][136]  (phase 1, resident W)
  unsigned short* Kb = lds;             // [352][40]  (phase 2, aliased)
  unsigned short* Vt = lds + 14080;     // [32][360]

  const float* xw = x + (size_t)w * (N * DIM);
  const int xsw = ((l31 >> 3) & 1) << 3;   // 1-bit swizzle for X frag reads
  const bool act = (wv < 11);

  // ---- staging geometry (fixed per thread) ----
  const int xrow0 = tid >> 2,  xg0 = (tid & 3) << 2;           // job 0 (all)
  const int idx1  = tid + 768;
  const int xrow1 = idx1 >> 2, xg1 = (idx1 & 3) << 2;          // job 1
  const bool hasx1 = (idx1 < 1408);
  const int xgs0 = xg0 ^ (((xrow0 >> 3) & 1) << 3);
  const int xgs1 = xg1 ^ (((xrow1 >> 3) & 1) << 3);

  float4v xr0v = {0.f, 0.f, 0.f, 0.f}, xr1v = {0.f, 0.f, 0.f, 0.f};

#define LOAD_STAGE(kc_)                                                     \
  {                                                                         \
    xr0v = *(const float4v*)(xw + xrow0 * DIM + (kc_) * 16 + xg0);          \
    xr1v[0] = 0.f; xr1v[1] = 0.f; xr1v[2] = 0.f; xr1v[3] = 0.f;             \
    if (hasx1 && xrow1 < N)                                                 \
      xr1v = *(const float4v*)(xw + xrow1 * DIM + (kc_) * 16 + xg1);        \
  }

#define WRITE_STAGE(XB_)                                                    \
  {                                                                         \
    unsigned h0_, h1_;                                                      \
    h0_ = cvtpk_bf16(xr0v[0], xr0v[1]);                                     \
    h1_ = cvtpk_bf16(xr0v[2], xr0v[3]);                                     \
    uint2v hv_ = {h0_, h1_};                                                \
    *(uint2v*)&(XB_)[xrow0 * 24 + xgs0] = hv_;                              \
    if (hasx1) {                                                            \
      h0_ = cvtpk_bf16(xr1v[0], xr1v[1]);                                   \
      h1_ = cvtpk_bf16(xr1v[2], xr1v[3]);                                   \
      uint2v hv2_ = {h0_, h1_};                                             \
      *(uint2v*)&(XB_)[xrow1 * 24 + xgs1] = hv2_;                           \
    }                                                                       \
  }

  f32x16 aQ, aK, aV;
#pragma unroll
  for (int r = 0; r < 16; ++r) { aQ[r] = 0.f; aK[r] = 0.f; aV[r] = 0.f; }

  // ---------------- Phase 1 prologue: X chunk 0 + resident W ----------------
  LOAD_STAGE(0);
  // one-time W stage: 3072 jobs (c 0..95, k-groups of 4)
#pragma unroll
  for (int p = 0; p < 4; ++p) {
    int idx = tid + p * 768;
    int c = idx % 96, kg = (idx / 96) << 2;
    int col = ((c >> 5) << 7) + h * DH + (c & 31);
    const float* wp = wqkv + (size_t)kg * 384 + col;
#pragma unroll
    for (int u = 0; u < 4; ++u)
      Wf[c * 136 + kg + u] = bf16u(wp[(size_t)u * 384]);
  }

  // ---------------- Phase 1 main: one barrier per kc ----------------
  for (int kc = 0; kc < 8; ++kc) {
    unsigned short* cur = (kc & 1) ? Xb1 : Xb0;
    WRITE_STAGE(cur);                 // regs from LOAD of last iter
    if (kc < 7) LOAD_STAGE(kc + 1);   // issue next chunk's loads NOW
    __syncthreads();                  // cur visible; (kc-2) reads retired

    if (act) {
      const int fo = (half * 8) ^ xsw;
      const int wfo = kc * 16 + half * 8;
      short8 xh = *(const short8*)&cur[(wv * 32 + l31) * 24 + fo];
      {  // Q: TRANSPOSED -> A = Wq, B = X
        short8 wh8 = *(const short8*)&Wf[l31 * 136 + wfo];
        aQ = MFMA(wh8, xh, aQ, 0, 0, 0);
      }
      {  // K: A = X, B = Wk
        short8 wh8 = *(const short8*)&Wf[(32 + l31) * 136 + wfo];
        aK = MFMA(xh, wh8, aK, 0, 0, 0);
      }
      {  // V: A = X, B = Wv
        short8 wh8 = *(const short8*)&Wf[(64 + l31) * 136 + wfo];
        aV = MFMA(xh, wh8, aV, 0, 0, 0);
      }
    }
  }

  __syncthreads();  // all X/W reads done; safe to overwrite with K/V

  // ---- Q^T acc -> phase-2 B-fragment, fully in registers ----
  const float QS = 0.17677669529663687f * 1.4426950408889634f;  // /sqrt(32)*log2e
  uint4v qA = {0, 0, 0, 0}, qB = {0, 0, 0, 0};
  const int swz = ((l31 >> 3) & 3) << 3;
  if (act) {
    unsigned g0 = cvtpk_bf16(aQ[0] * QS, aQ[1] * QS);
    unsigned g1 = cvtpk_bf16(aQ[2] * QS, aQ[3] * QS);
    unsigned g2 = cvtpk_bf16(aQ[4] * QS, aQ[5] * QS);
    unsigned g3 = cvtpk_bf16(aQ[6] * QS, aQ[7] * QS);
    unsigned g4 = cvtpk_bf16(aQ[8] * QS, aQ[9] * QS);
    unsigned g5 = cvtpk_bf16(aQ[10] * QS, aQ[11] * QS);
    unsigned g6 = cvtpk_bf16(aQ[12] * QS, aQ[13] * QS);
    unsigned g7 = cvtpk_bf16(aQ[14] * QS, aQ[15] * QS);
    swap32(g0, g2); swap32(g1, g3); swap32(g4, g6); swap32(g5, g7);
    qA[0] = g0; qA[1] = g1; qA[2] = g2; qA[3] = g3;
    qB[0] = g4; qB[1] = g5; qB[2] = g6; qB[3] = g7;

    // K -> LDS (2-bit XOR col swizzle)
#pragma unroll
    for (int r = 0; r < 16; ++r) {
      int iD = (r & 3) + ((r >> 2) << 3) + (half << 2);
      int cs = l31 ^ ((r >> 2) << 3);
      Kb[(wv * 32 + iD) * 40 + cs] = bf16u(aK[r]);
    }
    // V -> LDS transposed, stride 360, token-swizzled by (d&24)
#pragma unroll
    for (int r = 0; r < 16; r += 2) {
      int j0 = (r & 3) + ((r >> 2) << 3) + (half << 2);
      *(unsigned*)&Vt[l31 * 360 + wv * 32 + (j0 ^ swz)] =
          cvtpk_bf16(aV[r], aV[r + 1]);
    }
  }
  __syncthreads();

  // ---------------- Phase 2: attention ----------------
  if (act) {
    const float* bp = prep + ((size_t)(h * 22 + half) * NP) * 16;
    float* outw = out + (size_t)w * N * DIM + h * DH;
    attend(wv * 32, qA, qB, Kb, Vt, bp, outw, l31, half, swz);
  }
}

// ---------------------------------------------------------------------------
// Kernel 3: out-projection, in-place on d_out. Pure bf16 GEMM (O and W2
// single bf16). One block per window, 768 threads, M-tile per wave.
// ---------------------------------------------------------------------------
__global__ __launch_bounds__(768, 3) void proj_kernel(
    const float* __restrict__ wout, float* __restrict__ out) {
  const int w = blockIdx.x;
  const int tid = threadIdx.x;
  const int lane = tid & 63, wv = tid >> 6, l31 = lane & 31, half = lane >> 5;
  __shared__ __align__(16) unsigned short lds[19200];     // 38400 B
  unsigned short* Oh = lds;               // [352][40]
  unsigned short* W2h = lds + 14080;      // [128][40]
  float* ow = out + (size_t)w * N * DIM;
  const int swz = ((l31 >> 3) & 3) << 3;
  const bool act = (wv < 11);

  f32x16 acc[4];
#pragma unroll
  for (int s = 0; s < 4; ++s)
#pragma unroll
    for (int r = 0; r < 16; ++r) acc[s][r] = 0.f;

  for (int kc = 0; kc < 4; ++kc) {
    __syncthreads();
    // O staging: 2816 quad-groups (hi only)
#pragma unroll
    for (int p = 0; p < 4; ++p) {
      int idx = tid + p * 768;
      if (idx < 2816) {
        int row = idx >> 3, g = (idx & 7) << 2;
        float4v v = {0.f, 0.f, 0.f, 0.f};
        if (row < N) v = *(const float4v*)(ow + row * DIM + kc * 32 + g);
        unsigned h0 = cvtpk_bf16(v[0], v[1]);
        unsigned h1 = cvtpk_bf16(v[2], v[3]);
        uint2v hv = {h0, h1};
        int gs = g ^ (((row >> 3) & 3) << 3);
        *(uint2v*)&Oh[row * 40 + gs] = hv;
      }
    }
    // W2 staging: 1024 quad-jobs (hi only)
#pragma unroll
    for (int p = 0; p < 2; ++p) {
      int idx = tid + p * 768;
      if (idx < 1024) {
        int k = idx >> 5, n4 = (idx & 31) << 2;
        float4v v = *(const float4v*)(wout + (size_t)(kc * 32 + k) * DIM + n4);
#pragma unroll
        for (int u = 0; u < 4; ++u) {
          int n = n4 + u;
          int ks = k ^ (((n >> 3) & 3) << 3);
          W2h[n * 40 + ks] = bf16u(v[u]);
        }
      }
    }
    __syncthreads();
    if (act) {
#pragma unroll
      for (int kk = 0; kk < 2; ++kk) {
        int ro = (kk * 16 + half * 8) ^ swz;
        int rb = (wv * 32 + l31) * 40 + ro;
        short8 ah = *(const short8*)&Oh[rb];
#pragma unroll
        for (int s = 0; s < 4; ++s) {
          short8 bh = *(const short8*)&W2h[(s * 32 + l31) * 40 + ro];
          acc[s] = MFMA(ah, bh, acc[s], 0, 0, 0);
        }
      }
    }
  }
  if (act) {
#pragma unroll
    for (int s = 0; s < 4; ++s) {
#pragma unroll
      for (int r = 0; r < 16; ++r) {
        int iD = (r & 3) + ((r >> 2) << 3) + (half << 2);
        int i = wv * 32 + iD;
        if (i < N) ow[(size_t)i * DIM + s * 32 + l31] = acc[s][r];
      }
    }
  }
}

// ---------------------------------------------------------------------------
extern "C" void kernel_launch(void* const* d_in, const int* in_sizes, int n_in,
                              void* d_out, int out_size, void* d_ws, size_t ws_size,
                              hipStream_t stream) {
  const float* x     = (const float*)d_in[0];
  const float* wqkv  = (const float*)d_in[1];
  const float* wout  = (const float*)d_in[2];
  const float* table = (const float*)d_in[3];
  const int*   rel   = (const int*)d_in[4];
  float* out  = (float*)d_out;
  float* prep = (float*)d_ws;  // 4*11*2*352*16*4 B = 1.98 MB

  const int B = in_sizes[0] / (N * DIM);  // 512 windows
  const int rows = HEADS * 11 * 2 * NP;   // 30976

  bias_kernel<<<(rows + 255) / 256, 256, 0, stream>>>(table, rel, prep);
  attn_kernel<<<HEADS * B, 768, 0, stream>>>(x, wqkv, prep, out);
  proj_kernel<<<B, 768, 0, stream>>>(wout, out);
}